// Round 9
// baseline (337.043 us; speedup 1.0000x reference)
//
#include <hip/hip_runtime.h>
#include <hip/hip_bf16.h>
#include <hip/hip_fp16.h>

#define NN 100000
#define DIM 128
#define NB 391            // dst buckets of 256 nodes: (NN+255)>>8
#define BCAP 5120         // bucket capacity: lambda=4096, +16 sigma
#define GTILES ((NN + 63) / 64)   // 1563 row-tiles (64 rows each)
#define SEGN (NN * 16)    // halves per 16-col segment

typedef _Float16 f16x8 __attribute__((ext_vector_type(8)));
typedef float f32x4 __attribute__((ext_vector_type(4)));

// ---------------- tiny zero ----------------
__global__ void k_zero(int* __restrict__ p, int n) {
    int i = blockIdx.x * blockDim.x + threadIdx.x;
    if (i < n) p[i] = 0;
}

// ---------------- Phase A: bin edges by dst>>8, packed src|(dst&255)<<17 ----------------
__global__ void k_binA(const int* __restrict__ src, const int* __restrict__ dst,
                       int* __restrict__ bcur, int* __restrict__ binbuf, int E) {
    __shared__ int hist[NB];
    __shared__ int base[NB];
    const int t = threadIdx.x;
    for (int b = t; b < NB; b += 256) hist[b] = 0;
    __syncthreads();

    const int e0 = blockIdx.x * 4096;
    int mys[16], myd[16];
#pragma unroll
    for (int i = 0; i < 16; ++i) {
        const int e = e0 + i * 256 + t;
        int d = -1, s = 0;
        if (e < E) {
            d = dst[e];
            s = src[e];
            atomicAdd(&hist[d >> 8], 1);
        }
        mys[i] = s;
        myd[i] = d;
    }
    __syncthreads();

    for (int b = t; b < NB; b += 256) {
        const int h = hist[b];
        base[b] = h ? atomicAdd(&bcur[b], h) : 0;
    }
    __syncthreads();
    for (int b = t; b < NB; b += 256) hist[b] = 0;  // reuse as local cursor
    __syncthreads();

#pragma unroll
    for (int i = 0; i < 16; ++i) {
        const int d = myd[i];
        if (d >= 0) {
            const int b = d >> 8;
            const int loc = atomicAdd(&hist[b], 1);
            const int p = base[b] + loc;
            if (p < BCAP) binbuf[b * BCAP + p] = mys[i] | ((d & 255) << 17);
        }
    }
}

// ---------------- Phase B1: per-bucket degree count + dinv + bucket sum ----------------
__global__ void k_binCount(const int* __restrict__ bcur, const int* __restrict__ binbuf,
                           int* __restrict__ degi, float* __restrict__ dinv,
                           int* __restrict__ bsum) {
    __shared__ int cnt[256];
    __shared__ int red[256];
    const int b = blockIdx.x;
    const int t = threadIdx.x;
    cnt[t] = 0;
    __syncthreads();
    const int n = min(bcur[b], BCAP);
    const int* p = &binbuf[b * BCAP];
    for (int i = t; i < n; i += 256) atomicAdd(&cnt[p[i] >> 17], 1);
    __syncthreads();
    const int node = b * 256 + t;
    const int c = cnt[t];
    if (node < NN) {
        degi[node] = c;
        dinv[node] = rsqrtf((float)(c + 1));  // +1 self-loop
    }
    red[t] = (node < NN) ? c : 0;
    __syncthreads();
    for (int d = 128; d > 0; d >>= 1) {
        if (t < d) red[t] += red[t + d];
        __syncthreads();
    }
    if (t == 0) bsum[b] = red[0];
}

// ---------------- exclusive scan of bucket sums ----------------
__global__ void k_scan2(int* __restrict__ bsum, int nb) {
    __shared__ int s[1024];
    const int t = threadIdx.x;
    const int v = (t < nb) ? bsum[t] : 0;
    s[t] = v;
    __syncthreads();
    int acc = v;
    for (int d = 1; d < 1024; d <<= 1) {
        const int o = (t >= d) ? s[t - d] : 0;
        __syncthreads();
        acc += o;
        s[t] = acc;
        __syncthreads();
    }
    if (t < nb) bsum[t] = acc - v;  // exclusive
}

// ---------------- GEMM1 (MFMA, fp32 x in, seg-major fp16 out) + fused CSR fill blocks ----------------
__global__ void k_gemm1(const float* __restrict__ inF, const float* __restrict__ W,
                        const float* __restrict__ dinv, _Float16* __restrict__ outH,
                        const int* __restrict__ degi, const int* __restrict__ bsum,
                        int* __restrict__ rowptr, const int* __restrict__ bcur,
                        const int* __restrict__ binbuf, int* __restrict__ csr) {
    __shared__ int s[256];
    __shared__ int cur[256];
    const int t = threadIdx.x;

    if (blockIdx.x < NB) {
        const int b = blockIdx.x;
        const int node = b * 256 + t;
        const int deg = (node < NN) ? degi[node] : 0;
        s[t] = deg;
        __syncthreads();
        int acc = deg;
        for (int d = 1; d < 256; d <<= 1) {
            const int o = (t >= d) ? s[t - d] : 0;
            __syncthreads();
            acc += o;
            s[t] = acc;
            __syncthreads();
        }
        const int ex = acc - deg + bsum[b];
        cur[t] = ex;
        if (node < NN) {
            rowptr[node] = ex;
            if (node == NN - 1) rowptr[NN] = ex + deg;
        }
        __syncthreads();
        const int n = min(bcur[b], BCAP);
        const int* p = &binbuf[b * BCAP];
        for (int i = t; i < n; i += 256) {
            const int v = p[i];
            const int pos = atomicAdd(&cur[v >> 17], 1);
            csr[pos] = v & 0x1FFFF;
        }
        return;
    }

    const int tile = blockIdx.x - NB;
    const int row0 = tile * 64;
    const int wv   = t >> 6;
    const int l    = t & 63;
    const int l15  = l & 15;
    const int lk8  = (l >> 4) << 3;
    const int colw = wv << 5;

    f16x8 bf[2][4];
#pragma unroll
    for (int ct = 0; ct < 2; ++ct)
#pragma unroll
        for (int kt = 0; kt < 4; ++kt) {
            const int nn = colw + ct * 16 + l15;
            const int k0 = kt * 32 + lk8;
            f16x8 v;
#pragma unroll
            for (int j = 0; j < 8; ++j) v[j] = (_Float16)W[(k0 + j) * DIM + nn];
            bf[ct][kt] = v;
        }

    f32x4 acc[4][2];
#pragma unroll
    for (int rt = 0; rt < 4; ++rt)
#pragma unroll
        for (int ct = 0; ct < 2; ++ct) acc[rt][ct] = (f32x4){0.f, 0.f, 0.f, 0.f};

#pragma unroll
    for (int rt = 0; rt < 4; ++rt) {
        int row = row0 + rt * 16 + l15;
        row = min(row, NN - 1);
        f16x8 a[4];
#pragma unroll
        for (int kt = 0; kt < 4; ++kt) {
            const int k0 = kt * 32 + lk8;
            const float4 v0 = *(const float4*)&inF[row * DIM + k0];
            const float4 v1 = *(const float4*)&inF[row * DIM + k0 + 4];
            f16x8 v;
            v[0] = (_Float16)v0.x; v[1] = (_Float16)v0.y;
            v[2] = (_Float16)v0.z; v[3] = (_Float16)v0.w;
            v[4] = (_Float16)v1.x; v[5] = (_Float16)v1.y;
            v[6] = (_Float16)v1.z; v[7] = (_Float16)v1.w;
            a[kt] = v;
        }
#pragma unroll
        for (int ct = 0; ct < 2; ++ct)
#pragma unroll
            for (int kt = 0; kt < 4; ++kt)
                acc[rt][ct] = __builtin_amdgcn_mfma_f32_16x16x32_f16(a[kt], bf[ct][kt],
                                                                    acc[rt][ct], 0, 0, 0);
    }

    // epilogue: seg-major store — col = colw + ct*16 + l15 -> seg = 2*wv+ct, within = l15
#pragma unroll
    for (int rt = 0; rt < 4; ++rt)
#pragma unroll
        for (int r = 0; r < 4; ++r) {
            const int row = row0 + rt * 16 + ((l >> 4) << 2) + r;
            if (row < NN) {
                const float d = dinv[row];
                outH[(2 * wv + 0) * SEGN + row * 16 + l15] = (_Float16)(acc[rt][0][r] * d);
                outH[(2 * wv + 1) * SEGN + row * 16 + l15] = (_Float16)(acc[rt][1][r] * d);
            }
        }
}

// ---------------- GEMM2 (MFMA, row-major fp16 in [already relu'd], seg-major fp16 out) ----------------
__global__ void k_gemm2(const _Float16* __restrict__ inH, const float* __restrict__ W,
                        const float* __restrict__ dinv, _Float16* __restrict__ outH) {
    const int t = threadIdx.x;
    const int row0 = blockIdx.x * 64;
    const int wv   = t >> 6;
    const int l    = t & 63;
    const int l15  = l & 15;
    const int lk8  = (l >> 4) << 3;
    const int colw = wv << 5;

    f16x8 bf[2][4];
#pragma unroll
    for (int ct = 0; ct < 2; ++ct)
#pragma unroll
        for (int kt = 0; kt < 4; ++kt) {
            const int nn = colw + ct * 16 + l15;
            const int k0 = kt * 32 + lk8;
            f16x8 v;
#pragma unroll
            for (int j = 0; j < 8; ++j) v[j] = (_Float16)W[(k0 + j) * DIM + nn];
            bf[ct][kt] = v;
        }

    f32x4 acc[4][2];
#pragma unroll
    for (int rt = 0; rt < 4; ++rt)
#pragma unroll
        for (int ct = 0; ct < 2; ++ct) acc[rt][ct] = (f32x4){0.f, 0.f, 0.f, 0.f};

#pragma unroll
    for (int rt = 0; rt < 4; ++rt) {
        int row = row0 + rt * 16 + l15;
        row = min(row, NN - 1);
        f16x8 a[4];
#pragma unroll
        for (int kt = 0; kt < 4; ++kt)
            a[kt] = *(const f16x8*)&inH[row * DIM + kt * 32 + lk8];
#pragma unroll
        for (int ct = 0; ct < 2; ++ct)
#pragma unroll
            for (int kt = 0; kt < 4; ++kt)
                acc[rt][ct] = __builtin_amdgcn_mfma_f32_16x16x32_f16(a[kt], bf[ct][kt],
                                                                    acc[rt][ct], 0, 0, 0);
    }

#pragma unroll
    for (int rt = 0; rt < 4; ++rt)
#pragma unroll
        for (int r = 0; r < 4; ++r) {
            const int row = row0 + rt * 16 + ((l >> 4) << 2) + r;
            if (row < NN) {
                const float d = dinv[row];
                outH[(2 * wv + 0) * SEGN + row * 16 + l15] = (_Float16)(acc[rt][0][r] * d);
                outH[(2 * wv + 1) * SEGN + row * 16 + l15] = (_Float16)(acc[rt][1][r] * d);
            }
        }
}

// ---------------- segmented gather: seg = blockIdx&7 (XCD-pinned working set) ----------------
// 8-lane group per node, 16 fp16 cols per group (32B). 32 nodes/block.
// FINAL=0: aggH[n][col] = half(relu(dinv*acc + b1[col]))   (row-major, feeds GEMM2)
// FINAL=1: outF[n][col] = dinv*acc + b2[col]               (fp32 final output)
template <int FINAL>
__global__ void k_gather_seg(const _Float16* __restrict__ hsSeg, _Float16* __restrict__ aggH,
                             float* __restrict__ outF, const int* __restrict__ csr,
                             const int* __restrict__ rowptr, const float* __restrict__ dinv,
                             const float* __restrict__ bias) {
    const int seg   = blockIdx.x & 7;
    const int chunk = blockIdx.x >> 3;
    const int t     = threadIdx.x;
    const int wv    = t >> 6;
    const int lane  = t & 63;
    const int grp   = lane >> 3;      // 0..7
    const int gl    = lane & 7;       // 0..7 -> col pair
    const int n     = chunk * 32 + wv * 8 + grp;   // node (3125*32 = NN exactly)

    const _Float16* __restrict__ hp = hsSeg + seg * SEGN;
    const int col = seg * 16 + (gl << 1);

    const int start = rowptr[n];
    const int end   = rowptr[n + 1];

    float2 a0 = __half22float2(*(const __half2*)&hp[n * 16 + (gl << 1)]);  // self-loop
    float2 a1 = {0.f, 0.f};

    int j = start;
    for (; j + 1 < end; j += 2) {
        const int s0 = csr[j];
        const int s1 = csr[j + 1];
        const float2 v0 = __half22float2(*(const __half2*)&hp[s0 * 16 + (gl << 1)]);
        const float2 v1 = __half22float2(*(const __half2*)&hp[s1 * 16 + (gl << 1)]);
        a0.x += v0.x; a0.y += v0.y;
        a1.x += v1.x; a1.y += v1.y;
    }
    if (j < end) {
        const int s0 = csr[j];
        const float2 v0 = __half22float2(*(const __half2*)&hp[s0 * 16 + (gl << 1)]);
        a0.x += v0.x; a0.y += v0.y;
    }

    const float dn = dinv[n];
    const float2 bb = {bias[col], bias[col + 1]};
    if constexpr (FINAL) {
        float2 r;
        r.x = fmaf(dn, a0.x + a1.x, bb.x);
        r.y = fmaf(dn, a0.y + a1.y, bb.y);
        *(float2*)&outF[n * DIM + col] = r;
    } else {
        float2 r;
        r.x = fmaxf(fmaf(dn, a0.x + a1.x, bb.x), 0.f);
        r.y = fmaxf(fmaf(dn, a0.y + a1.y, bb.y), 0.f);
        *(__half2*)&aggH[n * DIM + col] = __floats2half2_rn(r.x, r.y);
    }
}

extern "C" void kernel_launch(void* const* d_in, const int* in_sizes, int n_in,
                              void* d_out, int out_size, void* d_ws, size_t ws_size,
                              hipStream_t stream) {
    const float* x  = (const float*)d_in[0];
    const int*   ei = (const int*)d_in[1];
    const float* W1 = (const float*)d_in[2];
    const float* b1 = (const float*)d_in[3];
    const float* W2 = (const float*)d_in[4];
    const float* b2 = (const float*)d_in[5];
    float* out = (float*)d_out;

    const int E = in_sizes[1] / 2;
    const int* src = ei;        // edge_index[0]
    const int* dst = ei + E;    // edge_index[1]

    char* ws = (char*)d_ws;
    float*    dinv   = (float*)(ws);                        // NN floats
    int*      degi   = (int*)  (ws + (1  << 20));           // NN ints
    int*      rowptr = (int*)  (ws + (2  << 20));           // NN+1 ints
    int*      bsum   = (int*)  (ws + (3  << 20));           // NB ints
    int*      bcur   = (int*)  (ws + (3  << 20) + 65536);   // NB ints
    int*      csr    = (int*)  (ws + (4  << 20));           // E ints (6.4 MB)
    int*      binbuf = (int*)  (ws + (11 << 20));           // NB*BCAP ints (8.0 MB)
    _Float16* hs     = (_Float16*)(ws + (20 << 20));        // seg-major, 25.6 MB
    _Float16* hs2    = (_Float16*)(ws + (47 << 20));        // seg-major, 25.6 MB
    _Float16* aggH   = (_Float16*)(ws + (74 << 20));        // row-major, 25.6 MB

    const int ABLK = (E + 4095) / 4096;                     // 391

    // ---- CSR build ----
    k_zero    <<<(NB + 255) / 256, 256, 0, stream>>>(bcur, NB);
    k_binA    <<<ABLK, 256, 0, stream>>>(src, dst, bcur, binbuf, E);
    k_binCount<<<NB, 256, 0, stream>>>(bcur, binbuf, degi, dinv, bsum);
    k_scan2   <<<1, 1024, 0, stream>>>(bsum, NB);

    // ---- layer 1: rowptr-scan + CSR fill (391 blocks) + MFMA GEMM1 ----
    k_gemm1<<<NB + GTILES, 256, 0, stream>>>(x, W1, dinv, hs, degi, bsum,
                                             rowptr, bcur, binbuf, csr);
    k_gather_seg<0><<<(NN / 32) * 8, 256, 0, stream>>>(hs, aggH, nullptr, csr, rowptr,
                                                       dinv, b1);

    // ---- layer 2 ----
    k_gemm2<<<GTILES, 256, 0, stream>>>(aggH, W2, dinv, hs2);
    k_gather_seg<1><<<(NN / 32) * 8, 256, 0, stream>>>(hs2, nullptr, out, csr, rowptr,
                                                       dinv, b2);
}

// Round 10
// 242.927 us; speedup vs baseline: 1.3874x; 1.3874x over previous
//
#include <hip/hip_runtime.h>
#include <hip/hip_bf16.h>
#include <hip/hip_fp16.h>

#define NN 100000
#define DIM 128
#define NB 391            // dst buckets of 256 nodes: (NN+255)>>8
#define BCAP 5120         // bucket capacity: lambda=4096, +16 sigma
#define GTILES ((NN + 63) / 64)   // 1563 row-tiles (64 rows each)

typedef _Float16 f16x8 __attribute__((ext_vector_type(8)));
typedef float f32x4 __attribute__((ext_vector_type(4)));

// ---------------- tiny zero ----------------
__global__ void k_zero(int* __restrict__ p, int n) {
    int i = blockIdx.x * blockDim.x + threadIdx.x;
    if (i < n) p[i] = 0;
}

// ---------------- Phase A: bin edges by dst>>8, packed src|(dst&255)<<17 ----------------
__global__ void k_binA(const int* __restrict__ src, const int* __restrict__ dst,
                       int* __restrict__ bcur, int* __restrict__ binbuf, int E) {
    __shared__ int hist[NB];
    __shared__ int base[NB];
    const int t = threadIdx.x;
    for (int b = t; b < NB; b += 256) hist[b] = 0;
    __syncthreads();

    const int e0 = blockIdx.x * 4096;
    int mys[16], myd[16];
#pragma unroll
    for (int i = 0; i < 16; ++i) {
        const int e = e0 + i * 256 + t;
        int d = -1, s = 0;
        if (e < E) {
            d = dst[e];
            s = src[e];
            atomicAdd(&hist[d >> 8], 1);
        }
        mys[i] = s;
        myd[i] = d;
    }
    __syncthreads();

    for (int b = t; b < NB; b += 256) {
        const int h = hist[b];
        base[b] = h ? atomicAdd(&bcur[b], h) : 0;
    }
    __syncthreads();
    for (int b = t; b < NB; b += 256) hist[b] = 0;  // reuse as local cursor
    __syncthreads();

#pragma unroll
    for (int i = 0; i < 16; ++i) {
        const int d = myd[i];
        if (d >= 0) {
            const int b = d >> 8;
            const int loc = atomicAdd(&hist[b], 1);
            const int p = base[b] + loc;
            if (p < BCAP) binbuf[b * BCAP + p] = mys[i] | ((d & 255) << 17);
        }
    }
}

// ---------------- Phase B1: per-bucket degree count + dinv + bucket sum ----------------
__global__ void k_binCount(const int* __restrict__ bcur, const int* __restrict__ binbuf,
                           int* __restrict__ degi, float* __restrict__ dinv,
                           int* __restrict__ bsum) {
    __shared__ int cnt[256];
    __shared__ int red[256];
    const int b = blockIdx.x;
    const int t = threadIdx.x;
    cnt[t] = 0;
    __syncthreads();
    const int n = min(bcur[b], BCAP);
    const int* p = &binbuf[b * BCAP];
    for (int i = t; i < n; i += 256) atomicAdd(&cnt[p[i] >> 17], 1);
    __syncthreads();
    const int node = b * 256 + t;
    const int c = cnt[t];
    if (node < NN) {
        degi[node] = c;
        dinv[node] = rsqrtf((float)(c + 1));  // +1 self-loop
    }
    red[t] = (node < NN) ? c : 0;
    __syncthreads();
    for (int d = 128; d > 0; d >>= 1) {
        if (t < d) red[t] += red[t + d];
        __syncthreads();
    }
    if (t == 0) bsum[b] = red[0];
}

// ---------------- exclusive scan of bucket sums ----------------
__global__ void k_scan2(int* __restrict__ bsum, int nb) {
    __shared__ int s[1024];
    const int t = threadIdx.x;
    const int v = (t < nb) ? bsum[t] : 0;
    s[t] = v;
    __syncthreads();
    int acc = v;
    for (int d = 1; d < 1024; d <<= 1) {
        const int o = (t >= d) ? s[t - d] : 0;
        __syncthreads();
        acc += o;
        s[t] = acc;
        __syncthreads();
    }
    if (t < nb) bsum[t] = acc - v;  // exclusive
}

// ---------------- GEMM1 (MFMA, fp32 x in, row-major fp16 out) + fused CSR fill blocks ----------------
__global__ void k_gemm1(const float* __restrict__ inF, const float* __restrict__ W,
                        const float* __restrict__ dinv, _Float16* __restrict__ outH,
                        const int* __restrict__ degi, const int* __restrict__ bsum,
                        int* __restrict__ rowptr, const int* __restrict__ bcur,
                        const int* __restrict__ binbuf, int* __restrict__ csr) {
    __shared__ int s[256];
    __shared__ int cur[256];
    const int t = threadIdx.x;

    if (blockIdx.x < NB) {
        const int b = blockIdx.x;
        const int node = b * 256 + t;
        const int deg = (node < NN) ? degi[node] : 0;
        s[t] = deg;
        __syncthreads();
        int acc = deg;
        for (int d = 1; d < 256; d <<= 1) {
            const int o = (t >= d) ? s[t - d] : 0;
            __syncthreads();
            acc += o;
            s[t] = acc;
            __syncthreads();
        }
        const int ex = acc - deg + bsum[b];
        cur[t] = ex;
        if (node < NN) {
            rowptr[node] = ex;
            if (node == NN - 1) rowptr[NN] = ex + deg;
        }
        __syncthreads();
        const int n = min(bcur[b], BCAP);
        const int* p = &binbuf[b * BCAP];
        for (int i = t; i < n; i += 256) {
            const int v = p[i];
            const int pos = atomicAdd(&cur[v >> 17], 1);
            csr[pos] = v & 0x1FFFF;
        }
        return;
    }

    const int tile = blockIdx.x - NB;
    const int row0 = tile * 64;
    const int wv   = t >> 6;
    const int l    = t & 63;
    const int l15  = l & 15;
    const int lk8  = (l >> 4) << 3;
    const int colw = wv << 5;

    f16x8 bf[2][4];
#pragma unroll
    for (int ct = 0; ct < 2; ++ct)
#pragma unroll
        for (int kt = 0; kt < 4; ++kt) {
            const int nn = colw + ct * 16 + l15;
            const int k0 = kt * 32 + lk8;
            f16x8 v;
#pragma unroll
            for (int j = 0; j < 8; ++j) v[j] = (_Float16)W[(k0 + j) * DIM + nn];
            bf[ct][kt] = v;
        }

    f32x4 acc[4][2];
#pragma unroll
    for (int rt = 0; rt < 4; ++rt)
#pragma unroll
        for (int ct = 0; ct < 2; ++ct) acc[rt][ct] = (f32x4){0.f, 0.f, 0.f, 0.f};

#pragma unroll
    for (int rt = 0; rt < 4; ++rt) {
        int row = row0 + rt * 16 + l15;
        row = min(row, NN - 1);
        f16x8 a[4];
#pragma unroll
        for (int kt = 0; kt < 4; ++kt) {
            const int k0 = kt * 32 + lk8;
            const float4 v0 = *(const float4*)&inF[row * DIM + k0];
            const float4 v1 = *(const float4*)&inF[row * DIM + k0 + 4];
            f16x8 v;
            v[0] = (_Float16)v0.x; v[1] = (_Float16)v0.y;
            v[2] = (_Float16)v0.z; v[3] = (_Float16)v0.w;
            v[4] = (_Float16)v1.x; v[5] = (_Float16)v1.y;
            v[6] = (_Float16)v1.z; v[7] = (_Float16)v1.w;
            a[kt] = v;
        }
#pragma unroll
        for (int ct = 0; ct < 2; ++ct)
#pragma unroll
            for (int kt = 0; kt < 4; ++kt)
                acc[rt][ct] = __builtin_amdgcn_mfma_f32_16x16x32_f16(a[kt], bf[ct][kt],
                                                                    acc[rt][ct], 0, 0, 0);
    }

#pragma unroll
    for (int rt = 0; rt < 4; ++rt)
#pragma unroll
        for (int r = 0; r < 4; ++r) {
            const int row = row0 + rt * 16 + ((l >> 4) << 2) + r;
            if (row < NN) {
                const float d = dinv[row];
                outH[row * DIM + colw + l15]      = (_Float16)(acc[rt][0][r] * d);
                outH[row * DIM + colw + 16 + l15] = (_Float16)(acc[rt][1][r] * d);
            }
        }
}

// ---------------- GEMM2 (MFMA, row-major fp16 in [already relu'd], row-major fp16 out) ----------------
__global__ void k_gemm2(const _Float16* __restrict__ inH, const float* __restrict__ W,
                        const float* __restrict__ dinv, _Float16* __restrict__ outH) {
    const int t = threadIdx.x;
    const int row0 = blockIdx.x * 64;
    const int wv   = t >> 6;
    const int l    = t & 63;
    const int l15  = l & 15;
    const int lk8  = (l >> 4) << 3;
    const int colw = wv << 5;

    f16x8 bf[2][4];
#pragma unroll
    for (int ct = 0; ct < 2; ++ct)
#pragma unroll
        for (int kt = 0; kt < 4; ++kt) {
            const int nn = colw + ct * 16 + l15;
            const int k0 = kt * 32 + lk8;
            f16x8 v;
#pragma unroll
            for (int j = 0; j < 8; ++j) v[j] = (_Float16)W[(k0 + j) * DIM + nn];
            bf[ct][kt] = v;
        }

    f32x4 acc[4][2];
#pragma unroll
    for (int rt = 0; rt < 4; ++rt)
#pragma unroll
        for (int ct = 0; ct < 2; ++ct) acc[rt][ct] = (f32x4){0.f, 0.f, 0.f, 0.f};

#pragma unroll
    for (int rt = 0; rt < 4; ++rt) {
        int row = row0 + rt * 16 + l15;
        row = min(row, NN - 1);
        f16x8 a[4];
#pragma unroll
        for (int kt = 0; kt < 4; ++kt)
            a[kt] = *(const f16x8*)&inH[row * DIM + kt * 32 + lk8];
#pragma unroll
        for (int ct = 0; ct < 2; ++ct)
#pragma unroll
            for (int kt = 0; kt < 4; ++kt)
                acc[rt][ct] = __builtin_amdgcn_mfma_f32_16x16x32_f16(a[kt], bf[ct][kt],
                                                                    acc[rt][ct], 0, 0, 0);
    }

#pragma unroll
    for (int rt = 0; rt < 4; ++rt)
#pragma unroll
        for (int r = 0; r < 4; ++r) {
            const int row = row0 + rt * 16 + ((l >> 4) << 2) + r;
            if (row < NN) {
                const float d = dinv[row];
                outH[row * DIM + colw + l15]      = (_Float16)(acc[rt][0][r] * d);
                outH[row * DIM + colw + 16 + l15] = (_Float16)(acc[rt][1][r] * d);
            }
        }
}

// ---------------- quarter-wave gather ----------------
// wave = node; lane quarter q in [0,4) handles edge j+q; lane covers 8 halves (16B).
// one int4 csr load (broadcast) + one uint4 row load per 4 edges.
__device__ __forceinline__ void addrow(float4& lo, float4& hi, uint4 v) {
    union { unsigned u; __half2 h; } c;
    c.u = v.x; { float2 f = __half22float2(c.h); lo.x += f.x; lo.y += f.y; }
    c.u = v.y; { float2 f = __half22float2(c.h); lo.z += f.x; lo.w += f.y; }
    c.u = v.z; { float2 f = __half22float2(c.h); hi.x += f.x; hi.y += f.y; }
    c.u = v.w; { float2 f = __half22float2(c.h); hi.z += f.x; hi.w += f.y; }
}

// FINAL=0: aggH[n] = half(relu(dinv*acc + bias))  (row-major fp16 for GEMM2)
// FINAL=1: outF[n] = dinv*acc + bias              (fp32 final)
template <int FINAL>
__global__ void k_gather(const _Float16* __restrict__ hs, _Float16* __restrict__ aggH,
                         float* __restrict__ outF, const int* __restrict__ csr,
                         const int* __restrict__ rowptr, const float* __restrict__ dinv,
                         const float* __restrict__ bias) {
    const int w = (blockIdx.x * blockDim.x + threadIdx.x) >> 6;
    if (w >= NN) return;
    const int lane = threadIdx.x & 63;
    const int q    = lane >> 4;        // quarter 0..3
    const int c8   = (lane & 15) << 3; // 8-half col base (16 lanes cover 128)

    const int start = __builtin_amdgcn_readfirstlane(rowptr[w]);
    const int end   = __builtin_amdgcn_readfirstlane(rowptr[w + 1]);

    float4 A0 = {0.f, 0.f, 0.f, 0.f}, A1 = {0.f, 0.f, 0.f, 0.f};
    float4 B0 = {0.f, 0.f, 0.f, 0.f}, B1 = {0.f, 0.f, 0.f, 0.f};

    // self-loop on quarter 0
    if (q == 0) {
        const uint4 v = *(const uint4*)&hs[w * DIM + c8];
        addrow(A0, A1, v);
    }

    int j = start;
    // align j to 4 (int4 csr loads need 16B alignment); solos on quarter 0
    {
        int pre = (4 - (j & 3)) & 3;
        pre = min(pre, end - j);
        for (int p = 0; p < pre; ++p, ++j) {
            const int sv = __builtin_amdgcn_readfirstlane(csr[j]);
            if (q == 0) {
                const uint4 v = *(const uint4*)&hs[sv * DIM + c8];
                addrow(B0, B1, v);
            }
        }
    }

    for (; j + 7 < end; j += 8) {
        const int4 sa = *(const int4*)&csr[j];
        const int4 sb = *(const int4*)&csr[j + 4];
        const int s0 = (q == 0) ? sa.x : (q == 1) ? sa.y : (q == 2) ? sa.z : sa.w;
        const int s1 = (q == 0) ? sb.x : (q == 1) ? sb.y : (q == 2) ? sb.z : sb.w;
        const uint4 r0 = *(const uint4*)&hs[s0 * DIM + c8];
        const uint4 r1 = *(const uint4*)&hs[s1 * DIM + c8];
        addrow(A0, A1, r0);
        addrow(B0, B1, r1);
    }
    if (j + 3 < end) {
        const int4 sa = *(const int4*)&csr[j];
        const int s0 = (q == 0) ? sa.x : (q == 1) ? sa.y : (q == 2) ? sa.z : sa.w;
        const uint4 r0 = *(const uint4*)&hs[s0 * DIM + c8];
        addrow(A0, A1, r0);
        j += 4;
    }
    for (; j < end; ++j) {  // <=3 leftovers on quarter 0
        const int sv = __builtin_amdgcn_readfirstlane(csr[j]);
        if (q == 0) {
            const uint4 v = *(const uint4*)&hs[sv * DIM + c8];
            addrow(B0, B1, v);
        }
    }

    A0.x += B0.x; A0.y += B0.y; A0.z += B0.z; A0.w += B0.w;
    A1.x += B1.x; A1.y += B1.y; A1.z += B1.z; A1.w += B1.w;

    // combine quarters: same c8 lives at lane, lane^16, lane^32, lane^48
    A0.x += __shfl_xor(A0.x, 16); A0.x += __shfl_xor(A0.x, 32);
    A0.y += __shfl_xor(A0.y, 16); A0.y += __shfl_xor(A0.y, 32);
    A0.z += __shfl_xor(A0.z, 16); A0.z += __shfl_xor(A0.z, 32);
    A0.w += __shfl_xor(A0.w, 16); A0.w += __shfl_xor(A0.w, 32);
    A1.x += __shfl_xor(A1.x, 16); A1.x += __shfl_xor(A1.x, 32);
    A1.y += __shfl_xor(A1.y, 16); A1.y += __shfl_xor(A1.y, 32);
    A1.z += __shfl_xor(A1.z, 16); A1.z += __shfl_xor(A1.z, 32);
    A1.w += __shfl_xor(A1.w, 16); A1.w += __shfl_xor(A1.w, 32);

    if (q == 0) {
        const float d = dinv[w];
        const float4 bb0 = *(const float4*)&bias[c8];
        const float4 bb1 = *(const float4*)&bias[c8 + 4];
        if constexpr (FINAL) {
            float4 o0, o1;
            o0.x = fmaf(d, A0.x, bb0.x); o0.y = fmaf(d, A0.y, bb0.y);
            o0.z = fmaf(d, A0.z, bb0.z); o0.w = fmaf(d, A0.w, bb0.w);
            o1.x = fmaf(d, A1.x, bb1.x); o1.y = fmaf(d, A1.y, bb1.y);
            o1.z = fmaf(d, A1.z, bb1.z); o1.w = fmaf(d, A1.w, bb1.w);
            *(float4*)&outF[w * DIM + c8]     = o0;
            *(float4*)&outF[w * DIM + c8 + 4] = o1;
        } else {
            union { __half2 h2[4]; uint4 u; } pk;
            pk.h2[0] = __floats2half2_rn(fmaxf(fmaf(d, A0.x, bb0.x), 0.f),
                                         fmaxf(fmaf(d, A0.y, bb0.y), 0.f));
            pk.h2[1] = __floats2half2_rn(fmaxf(fmaf(d, A0.z, bb0.z), 0.f),
                                         fmaxf(fmaf(d, A0.w, bb0.w), 0.f));
            pk.h2[2] = __floats2half2_rn(fmaxf(fmaf(d, A1.x, bb1.x), 0.f),
                                         fmaxf(fmaf(d, A1.y, bb1.y), 0.f));
            pk.h2[3] = __floats2half2_rn(fmaxf(fmaf(d, A1.z, bb1.z), 0.f),
                                         fmaxf(fmaf(d, A1.w, bb1.w), 0.f));
            *(uint4*)&aggH[w * DIM + c8] = pk.u;
        }
    }
}

extern "C" void kernel_launch(void* const* d_in, const int* in_sizes, int n_in,
                              void* d_out, int out_size, void* d_ws, size_t ws_size,
                              hipStream_t stream) {
    const float* x  = (const float*)d_in[0];
    const int*   ei = (const int*)d_in[1];
    const float* W1 = (const float*)d_in[2];
    const float* b1 = (const float*)d_in[3];
    const float* W2 = (const float*)d_in[4];
    const float* b2 = (const float*)d_in[5];
    float* out = (float*)d_out;

    const int E = in_sizes[1] / 2;
    const int* src = ei;        // edge_index[0]
    const int* dst = ei + E;    // edge_index[1]

    char* ws = (char*)d_ws;
    float*    dinv   = (float*)(ws);                        // NN floats
    int*      degi   = (int*)  (ws + (1  << 20));           // NN ints
    int*      rowptr = (int*)  (ws + (2  << 20));           // NN+1 ints
    int*      bsum   = (int*)  (ws + (3  << 20));           // NB ints
    int*      bcur   = (int*)  (ws + (3  << 20) + 65536);   // NB ints
    int*      csr    = (int*)  (ws + (4  << 20));           // E ints (6.4 MB)
    int*      binbuf = (int*)  (ws + (11 << 20));           // NB*BCAP ints (8.0 MB)
    _Float16* hs     = (_Float16*)(ws + (20 << 20));        // row-major, 25.6 MB
    _Float16* aggH   = (_Float16*)(ws + (47 << 20));        // row-major, 25.6 MB
    _Float16* hs2    = (_Float16*)(ws + (74 << 20));        // row-major, 25.6 MB

    const int ABLK = (E + 4095) / 4096;                     // 391

    // ---- CSR build ----
    k_zero    <<<(NB + 255) / 256, 256, 0, stream>>>(bcur, NB);
    k_binA    <<<ABLK, 256, 0, stream>>>(src, dst, bcur, binbuf, E);
    k_binCount<<<NB, 256, 0, stream>>>(bcur, binbuf, degi, dinv, bsum);
    k_scan2   <<<1, 1024, 0, stream>>>(bsum, NB);

    // ---- layer 1: rowptr-scan + CSR fill (391 blocks) + MFMA GEMM1 ----
    k_gemm1<<<NB + GTILES, 256, 0, stream>>>(x, W1, dinv, hs, degi, bsum,
                                             rowptr, bcur, binbuf, csr);
    k_gather<0><<<(NN * 64) / 256, 256, 0, stream>>>(hs, aggH, nullptr, csr, rowptr,
                                                     dinv, b1);

    // ---- layer 2 ----
    k_gemm2<<<GTILES, 256, 0, stream>>>(aggH, W2, dinv, hs2);
    k_gather<1><<<(NN * 64) / 256, 256, 0, stream>>>(hs2, nullptr, out, csr, rowptr,
                                                     dinv, b2);
}

// Round 11
// 225.725 us; speedup vs baseline: 1.4932x; 1.0762x over previous
//
#include <hip/hip_runtime.h>
#include <hip/hip_bf16.h>
#include <hip/hip_fp16.h>

#define NN 100000
#define DIM 128
#define NB 391            // dst buckets of 256 nodes: (NN+255)>>8
#define BCAP 5120         // bucket capacity: lambda=4096, +16 sigma
#define GTILES ((NN + 63) / 64)   // 1563 row-tiles (64 rows each)
#define STP 130           // LDS store-stage padded row (halves): 260B stride -> 2-way banks

typedef _Float16 f16x8 __attribute__((ext_vector_type(8)));
typedef float f32x4 __attribute__((ext_vector_type(4)));

// ---------------- tiny zero ----------------
__global__ void k_zero(int* __restrict__ p, int n) {
    int i = blockIdx.x * blockDim.x + threadIdx.x;
    if (i < n) p[i] = 0;
}

// ---------------- Phase A: bin edges by dst>>8; per-wave hist to cut LDS-atomic contention ----------------
__global__ void k_binA(const int* __restrict__ src, const int* __restrict__ dst,
                       int* __restrict__ bcur, int* __restrict__ binbuf, int E) {
    __shared__ int hist[4][NB];
    const int t  = threadIdx.x;
    const int wv = t >> 6;
    for (int i = t; i < 4 * NB; i += 256) ((int*)hist)[i] = 0;
    __syncthreads();

    const int e0 = blockIdx.x * 4096;
    int mys[16], myd[16];
#pragma unroll
    for (int i = 0; i < 16; ++i) {
        const int e = e0 + i * 256 + t;
        int d = -1, s = 0;
        if (e < E) {
            d = dst[e];
            s = src[e];
            atomicAdd(&hist[wv][d >> 8], 1);
        }
        mys[i] = s;
        myd[i] = d;
    }
    __syncthreads();

    // combine: reserve global range per bucket, convert slices to per-wave bucket-relative bases
    for (int b = t; b < NB; b += 256) {
        const int h0 = hist[0][b], h1 = hist[1][b], h2 = hist[2][b], h3 = hist[3][b];
        const int tot = h0 + h1 + h2 + h3;
        const int base = tot ? atomicAdd(&bcur[b], tot) : 0;
        hist[0][b] = base;
        hist[1][b] = base + h0;
        hist[2][b] = base + h0 + h1;
        hist[3][b] = base + h0 + h1 + h2;
    }
    __syncthreads();

#pragma unroll
    for (int i = 0; i < 16; ++i) {
        const int d = myd[i];
        if (d >= 0) {
            const int b = d >> 8;
            const int p = atomicAdd(&hist[wv][b], 1);  // bucket-relative position
            if (p < BCAP) binbuf[b * BCAP + p] = mys[i] | ((d & 255) << 17);
        }
    }
}

// ---------------- Phase B1: per-bucket degree count (per-wave cnt) + dinv + bucket sum ----------------
__global__ void k_binCount(const int* __restrict__ bcur, const int* __restrict__ binbuf,
                           int* __restrict__ degi, float* __restrict__ dinv,
                           int* __restrict__ bsum) {
    __shared__ int cnt[4][256];
    __shared__ int red[256];
    const int b  = blockIdx.x;
    const int t  = threadIdx.x;
    const int wv = t >> 6;
#pragma unroll
    for (int w = 0; w < 4; ++w) cnt[w][t] = 0;
    __syncthreads();
    const int n = min(bcur[b], BCAP);
    const int* p = &binbuf[b * BCAP];
    for (int i = t; i < n; i += 256) atomicAdd(&cnt[wv][p[i] >> 17], 1);
    __syncthreads();
    const int node = b * 256 + t;
    const int c = cnt[0][t] + cnt[1][t] + cnt[2][t] + cnt[3][t];
    if (node < NN) {
        degi[node] = c;
        dinv[node] = rsqrtf((float)(c + 1));  // +1 self-loop
    }
    red[t] = (node < NN) ? c : 0;
    __syncthreads();
    for (int d = 128; d > 0; d >>= 1) {
        if (t < d) red[t] += red[t + d];
        __syncthreads();
    }
    if (t == 0) bsum[b] = red[0];
}

// ---------------- exclusive scan of bucket sums ----------------
__global__ void k_scan2(int* __restrict__ bsum, int nb) {
    __shared__ int s[1024];
    const int t = threadIdx.x;
    const int v = (t < nb) ? bsum[t] : 0;
    s[t] = v;
    __syncthreads();
    int acc = v;
    for (int d = 1; d < 1024; d <<= 1) {
        const int o = (t >= d) ? s[t - d] : 0;
        __syncthreads();
        acc += o;
        s[t] = acc;
        __syncthreads();
    }
    if (t < nb) bsum[t] = acc - v;  // exclusive
}

// ---------------- GEMM1 (MFMA, fp32 x in, fp16 out, LDS-staged stores) + fused CSR fill ----------------
__global__ void k_gemm1(const float* __restrict__ inF, const float* __restrict__ W,
                        const float* __restrict__ dinv, _Float16* __restrict__ outH,
                        const int* __restrict__ degi, const int* __restrict__ bsum,
                        int* __restrict__ rowptr, const int* __restrict__ bcur,
                        const int* __restrict__ binbuf, int* __restrict__ csr) {
    __shared__ int s[256];
    __shared__ int cur[256];
    __shared__ _Float16 st[64][STP];
    const int t = threadIdx.x;

    if (blockIdx.x < NB) {
        const int b = blockIdx.x;
        const int node = b * 256 + t;
        const int deg = (node < NN) ? degi[node] : 0;
        s[t] = deg;
        __syncthreads();
        int acc = deg;
        for (int d = 1; d < 256; d <<= 1) {
            const int o = (t >= d) ? s[t - d] : 0;
            __syncthreads();
            acc += o;
            s[t] = acc;
            __syncthreads();
        }
        const int ex = acc - deg + bsum[b];
        cur[t] = ex;
        if (node < NN) {
            rowptr[node] = ex;
            if (node == NN - 1) rowptr[NN] = ex + deg;
        }
        __syncthreads();
        const int n = min(bcur[b], BCAP);
        const int* p = &binbuf[b * BCAP];
        for (int i = t; i < n; i += 256) {
            const int v = p[i];
            const int pos = atomicAdd(&cur[v >> 17], 1);
            csr[pos] = v & 0x1FFFF;
        }
        return;
    }

    const int tile = blockIdx.x - NB;
    const int row0 = tile * 64;
    const int wv   = t >> 6;
    const int l    = t & 63;
    const int l15  = l & 15;
    const int lk8  = (l >> 4) << 3;
    const int colw = wv << 5;

    f16x8 bf[2][4];
#pragma unroll
    for (int ct = 0; ct < 2; ++ct)
#pragma unroll
        for (int kt = 0; kt < 4; ++kt) {
            const int nn = colw + ct * 16 + l15;
            const int k0 = kt * 32 + lk8;
            f16x8 v;
#pragma unroll
            for (int j = 0; j < 8; ++j) v[j] = (_Float16)W[(k0 + j) * DIM + nn];
            bf[ct][kt] = v;
        }

    f32x4 acc[4][2];
#pragma unroll
    for (int rt = 0; rt < 4; ++rt)
#pragma unroll
        for (int ct = 0; ct < 2; ++ct) acc[rt][ct] = (f32x4){0.f, 0.f, 0.f, 0.f};

#pragma unroll
    for (int rt = 0; rt < 4; ++rt) {
        int row = row0 + rt * 16 + l15;
        row = min(row, NN - 1);
        f16x8 a[4];
#pragma unroll
        for (int kt = 0; kt < 4; ++kt) {
            const int k0 = kt * 32 + lk8;
            const float4 v0 = *(const float4*)&inF[row * DIM + k0];
            const float4 v1 = *(const float4*)&inF[row * DIM + k0 + 4];
            f16x8 v;
            v[0] = (_Float16)v0.x; v[1] = (_Float16)v0.y;
            v[2] = (_Float16)v0.z; v[3] = (_Float16)v0.w;
            v[4] = (_Float16)v1.x; v[5] = (_Float16)v1.y;
            v[6] = (_Float16)v1.z; v[7] = (_Float16)v1.w;
            a[kt] = v;
        }
#pragma unroll
        for (int ct = 0; ct < 2; ++ct)
#pragma unroll
            for (int kt = 0; kt < 4; ++kt)
                acc[rt][ct] = __builtin_amdgcn_mfma_f32_16x16x32_f16(a[kt], bf[ct][kt],
                                                                    acc[rt][ct], 0, 0, 0);
    }

    // epilogue: stage in LDS, then 256B-contiguous vector stores
#pragma unroll
    for (int rt = 0; rt < 4; ++rt)
#pragma unroll
        for (int r = 0; r < 4; ++r) {
            const int lr = rt * 16 + ((l >> 4) << 2) + r;
            const float d = dinv[min(row0 + lr, NN - 1)];
            st[lr][colw + l15]      = (_Float16)(acc[rt][0][r] * d);
            st[lr][colw + 16 + l15] = (_Float16)(acc[rt][1][r] * d);
        }
    __syncthreads();
#pragma unroll
    for (int i = 0; i < 4; ++i) {
        const int lr  = (wv << 4) + (i << 2) + (l >> 4);
        const int row = row0 + lr;
        if (row < NN) {
            const uint4 v = *(const uint4*)&st[lr][l15 << 3];
            *(uint4*)&outH[row * DIM + (l15 << 3)] = v;
        }
    }
}

// ---------------- GEMM2 (MFMA, fp16 in [already relu'd], fp16 out, LDS-staged stores) ----------------
__global__ void k_gemm2(const _Float16* __restrict__ inH, const float* __restrict__ W,
                        const float* __restrict__ dinv, _Float16* __restrict__ outH) {
    __shared__ _Float16 st[64][STP];
    const int t = threadIdx.x;
    const int row0 = blockIdx.x * 64;
    const int wv   = t >> 6;
    const int l    = t & 63;
    const int l15  = l & 15;
    const int lk8  = (l >> 4) << 3;
    const int colw = wv << 5;

    f16x8 bf[2][4];
#pragma unroll
    for (int ct = 0; ct < 2; ++ct)
#pragma unroll
        for (int kt = 0; kt < 4; ++kt) {
            const int nn = colw + ct * 16 + l15;
            const int k0 = kt * 32 + lk8;
            f16x8 v;
#pragma unroll
            for (int j = 0; j < 8; ++j) v[j] = (_Float16)W[(k0 + j) * DIM + nn];
            bf[ct][kt] = v;
        }

    f32x4 acc[4][2];
#pragma unroll
    for (int rt = 0; rt < 4; ++rt)
#pragma unroll
        for (int ct = 0; ct < 2; ++ct) acc[rt][ct] = (f32x4){0.f, 0.f, 0.f, 0.f};

#pragma unroll
    for (int rt = 0; rt < 4; ++rt) {
        int row = row0 + rt * 16 + l15;
        row = min(row, NN - 1);
        f16x8 a[4];
#pragma unroll
        for (int kt = 0; kt < 4; ++kt)
            a[kt] = *(const f16x8*)&inH[row * DIM + kt * 32 + lk8];
#pragma unroll
        for (int ct = 0; ct < 2; ++ct)
#pragma unroll
            for (int kt = 0; kt < 4; ++kt)
                acc[rt][ct] = __builtin_amdgcn_mfma_f32_16x16x32_f16(a[kt], bf[ct][kt],
                                                                    acc[rt][ct], 0, 0, 0);
    }

#pragma unroll
    for (int rt = 0; rt < 4; ++rt)
#pragma unroll
        for (int r = 0; r < 4; ++r) {
            const int lr = rt * 16 + ((l >> 4) << 2) + r;
            const float d = dinv[min(row0 + lr, NN - 1)];
            st[lr][colw + l15]      = (_Float16)(acc[rt][0][r] * d);
            st[lr][colw + 16 + l15] = (_Float16)(acc[rt][1][r] * d);
        }
    __syncthreads();
#pragma unroll
    for (int i = 0; i < 4; ++i) {
        const int lr  = (wv << 4) + (i << 2) + (l >> 4);
        const int row = row0 + lr;
        if (row < NN) {
            const uint4 v = *(const uint4*)&st[lr][l15 << 3];
            *(uint4*)&outH[row * DIM + (l15 << 3)] = v;
        }
    }
}

// ---------------- gather (R7-proven shape): wave=node, half2/lane, 4-unroll ----------------
// FINAL=0: aggH[n] = half(relu(dinv*acc + bias))  (row-major fp16 for GEMM2)
// FINAL=1: outF[n] = dinv*acc + bias              (fp32 final)
template <int FINAL>
__global__ void k_gather(const _Float16* __restrict__ hsp, _Float16* __restrict__ aggH,
                         float* __restrict__ outF, const int* __restrict__ csr,
                         const int* __restrict__ rowptr, const float* __restrict__ dinv,
                         const float* __restrict__ bias) {
    const __half* __restrict__ hs = (const __half*)hsp;
    const int w = (blockIdx.x * blockDim.x + threadIdx.x) >> 6;
    if (w >= NN) return;
    const int lane = threadIdx.x & 63;
    const int off  = lane << 1;

    const int start = __builtin_amdgcn_readfirstlane(rowptr[w]);
    const int end   = __builtin_amdgcn_readfirstlane(rowptr[w + 1]);

    float2 a0 = __half22float2(*(const __half2*)&hs[w * DIM + off]);  // self-loop
    float2 a1 = {0.f, 0.f}, a2 = {0.f, 0.f}, a3 = {0.f, 0.f};

    int j = start;
    for (; j + 3 < end; j += 4) {
        const int s0 = __builtin_amdgcn_readfirstlane(csr[j]);
        const int s1 = __builtin_amdgcn_readfirstlane(csr[j + 1]);
        const int s2 = __builtin_amdgcn_readfirstlane(csr[j + 2]);
        const int s3 = __builtin_amdgcn_readfirstlane(csr[j + 3]);
        const float2 v0 = __half22float2(*(const __half2*)&hs[s0 * DIM + off]);
        const float2 v1 = __half22float2(*(const __half2*)&hs[s1 * DIM + off]);
        const float2 v2 = __half22float2(*(const __half2*)&hs[s2 * DIM + off]);
        const float2 v3 = __half22float2(*(const __half2*)&hs[s3 * DIM + off]);
        a0.x += v0.x; a0.y += v0.y;
        a1.x += v1.x; a1.y += v1.y;
        a2.x += v2.x; a2.y += v2.y;
        a3.x += v3.x; a3.y += v3.y;
    }
    for (; j < end; ++j) {
        const int s0 = __builtin_amdgcn_readfirstlane(csr[j]);
        const float2 v0 = __half22float2(*(const __half2*)&hs[s0 * DIM + off]);
        a0.x += v0.x; a0.y += v0.y;
    }

    const float d = dinv[w];
    const float2 bb = {bias[off], bias[off + 1]};
    float2 r = {a0.x + a1.x + a2.x + a3.x, a0.y + a1.y + a2.y + a3.y};
    if constexpr (FINAL) {
        float2 o;
        o.x = fmaf(d, r.x, bb.x);
        o.y = fmaf(d, r.y, bb.y);
        *(float2*)&outF[w * DIM + off] = o;
    } else {
        r.x = fmaxf(fmaf(d, r.x, bb.x), 0.f);
        r.y = fmaxf(fmaf(d, r.y, bb.y), 0.f);
        *(__half2*)&aggH[w * DIM + off] = __floats2half2_rn(r.x, r.y);
    }
}

extern "C" void kernel_launch(void* const* d_in, const int* in_sizes, int n_in,
                              void* d_out, int out_size, void* d_ws, size_t ws_size,
                              hipStream_t stream) {
    const float* x  = (const float*)d_in[0];
    const int*   ei = (const int*)d_in[1];
    const float* W1 = (const float*)d_in[2];
    const float* b1 = (const float*)d_in[3];
    const float* W2 = (const float*)d_in[4];
    const float* b2 = (const float*)d_in[5];
    float* out = (float*)d_out;

    const int E = in_sizes[1] / 2;
    const int* src = ei;        // edge_index[0]
    const int* dst = ei + E;    // edge_index[1]

    char* ws = (char*)d_ws;
    float*    dinv   = (float*)(ws);                        // NN floats
    int*      degi   = (int*)  (ws + (1  << 20));           // NN ints
    int*      rowptr = (int*)  (ws + (2  << 20));           // NN+1 ints
    int*      bsum   = (int*)  (ws + (3  << 20));           // NB ints
    int*      bcur   = (int*)  (ws + (3  << 20) + 65536);   // NB ints
    int*      csr    = (int*)  (ws + (4  << 20));           // E ints (6.4 MB)
    int*      binbuf = (int*)  (ws + (11 << 20));           // NB*BCAP ints (8.0 MB)
    _Float16* hs     = (_Float16*)(ws + (20 << 20));        // row-major, 25.6 MB
    _Float16* aggH   = (_Float16*)(ws + (47 << 20));        // row-major, 25.6 MB
    _Float16* hs2    = (_Float16*)(ws + (74 << 20));        // row-major, 25.6 MB

    const int ABLK = (E + 4095) / 4096;                     // 391

    // ---- CSR build ----
    k_zero    <<<(NB + 255) / 256, 256, 0, stream>>>(bcur, NB);
    k_binA    <<<ABLK, 256, 0, stream>>>(src, dst, bcur, binbuf, E);
    k_binCount<<<NB, 256, 0, stream>>>(bcur, binbuf, degi, dinv, bsum);
    k_scan2   <<<1, 1024, 0, stream>>>(bsum, NB);

    // ---- layer 1: rowptr-scan + CSR fill (391 blocks) + MFMA GEMM1 ----
    k_gemm1<<<NB + GTILES, 256, 0, stream>>>(x, W1, dinv, hs, degi, bsum,
                                             rowptr, bcur, binbuf, csr);
    k_gather<0><<<(NN * 64) / 256, 256, 0, stream>>>(hs, aggH, nullptr, csr, rowptr,
                                                     dinv, b1);

    // ---- layer 2 ----
    k_gemm2<<<GTILES, 256, 0, stream>>>(aggH, W2, dinv, hs2);
    k_gather<1><<<(NN * 64) / 256, 256, 0, stream>>>(hs2, nullptr, out, csr, rowptr,
                                                     dinv, b2);
}

// Round 12
// 225.654 us; speedup vs baseline: 1.4936x; 1.0003x over previous
//
#include <hip/hip_runtime.h>
#include <hip/hip_bf16.h>
#include <hip/hip_fp16.h>

#define NN 100000
#define DIM 128
#define NB 391            // dst buckets of 256 nodes
#define BCAP 5120         // bucket capacity: lambda=4096, +16 sigma
#define GTILES ((NN + 63) / 64)   // 1563 row-tiles
#define STP 130           // LDS store-stage padded row (halves)

typedef _Float16 f16x8 __attribute__((ext_vector_type(8)));
typedef float f32x4 __attribute__((ext_vector_type(4)));

// ---------------- init: zero bcur + W1,W2 -> fp16 col-major (vectorizable MFMA frags) ----------------
__global__ void k_init(const float* __restrict__ W1, const float* __restrict__ W2,
                       int* __restrict__ bcur, _Float16* __restrict__ Wt1,
                       _Float16* __restrict__ Wt2) {
    const int b = blockIdx.x;
    const int t = threadIdx.x;
    if (b < 2) {
        const int i = b * 256 + t;
        if (i < NB) bcur[i] = 0;
        return;
    }
    const int idx = (b - 2) * 256 + t;       // 0..32767
    const int which = idx >> 14;
    const int i = idx & 16383;
    const int n = i >> 7, k = i & 127;
    if (which == 0) Wt1[n * DIM + k] = (_Float16)W1[k * DIM + n];
    else            Wt2[n * DIM + k] = (_Float16)W2[k * DIM + n];
}

// ---------------- Phase A: bin edges by dst>>8; per-wave hist ----------------
__global__ void k_binA(const int* __restrict__ src, const int* __restrict__ dst,
                       int* __restrict__ bcur, int* __restrict__ binbuf, int E) {
    __shared__ int hist[4][NB];
    const int t  = threadIdx.x;
    const int wv = t >> 6;
    for (int i = t; i < 4 * NB; i += 256) ((int*)hist)[i] = 0;
    __syncthreads();

    const int e0 = blockIdx.x * 4096;
    int mys[16], myd[16];
#pragma unroll
    for (int i = 0; i < 16; ++i) {
        const int e = e0 + i * 256 + t;
        int d = -1, s = 0;
        if (e < E) {
            d = dst[e];
            s = src[e];
            atomicAdd(&hist[wv][d >> 8], 1);
        }
        mys[i] = s;
        myd[i] = d;
    }
    __syncthreads();

    for (int b = t; b < NB; b += 256) {
        const int h0 = hist[0][b], h1 = hist[1][b], h2 = hist[2][b], h3 = hist[3][b];
        const int tot = h0 + h1 + h2 + h3;
        const int base = tot ? atomicAdd(&bcur[b], tot) : 0;
        hist[0][b] = base;
        hist[1][b] = base + h0;
        hist[2][b] = base + h0 + h1;
        hist[3][b] = base + h0 + h1 + h2;
    }
    __syncthreads();

#pragma unroll
    for (int i = 0; i < 16; ++i) {
        const int d = myd[i];
        if (d >= 0) {
            const int b = d >> 8;
            const int p = atomicAdd(&hist[wv][b], 1);
            if (p < BCAP) binbuf[b * BCAP + p] = mys[i] | ((d & 255) << 17);
        }
    }
}

// ---------------- exclusive scan of bucket totals (bcur -> bbase) ----------------
__global__ void k_scan2(const int* __restrict__ bcur, int* __restrict__ bbase, int nb) {
    __shared__ int s[512];
    const int t = threadIdx.x;
    const int v = (t < nb) ? bcur[t] : 0;
    s[t] = v;
    __syncthreads();
    int acc = v;
    for (int d = 1; d < 512; d <<= 1) {
        const int o = (t >= d) ? s[t - d] : 0;
        __syncthreads();
        acc += o;
        s[t] = acc;
        __syncthreads();
    }
    if (t < nb) bbase[t] = acc - v;  // exclusive
}

// ---------------- fused: CSR fill (hist+rowptr+dinv+fill) blocks + GEMM1 blocks ----------------
// fill blocks [0,NB): per-wave LDS hist over binbuf bucket -> deg, dinv, rowptr (bbase[b]+scan),
//                     per-wave cursors -> csr fill.
// gemm blocks [NB,..): hs = half(x @ W1)  [NO dinv scale -- deferred to gather1]
__global__ void k_gemm1(const float* __restrict__ inF, const _Float16* __restrict__ Wt,
                        _Float16* __restrict__ outH, const int* __restrict__ bbase,
                        const int* __restrict__ bcur, const int* __restrict__ binbuf,
                        int* __restrict__ rowptr, float* __restrict__ dinv,
                        int* __restrict__ csr) {
    __shared__ int cnt4[4][256];
    __shared__ int sc[256];
    __shared__ _Float16 st[64][STP];
    const int t  = threadIdx.x;
    const int wv = t >> 6;

    if (blockIdx.x < NB) {
        const int b = blockIdx.x;
        const int node = b * 256 + t;
#pragma unroll
        for (int w = 0; w < 4; ++w) cnt4[w][t] = 0;
        __syncthreads();
        const int n_e = min(bcur[b], BCAP);
        const int* p = &binbuf[b * BCAP];
        for (int i = t; i < n_e; i += 256) atomicAdd(&cnt4[wv][p[i] >> 17], 1);
        __syncthreads();
        const int c0 = cnt4[0][t], c1 = cnt4[1][t], c2 = cnt4[2][t], c3 = cnt4[3][t];
        const int c = c0 + c1 + c2 + c3;
        if (node < NN) dinv[node] = rsqrtf((float)(c + 1));  // +1 self-loop
        sc[t] = c;
        __syncthreads();
        int acc = c;
        for (int d = 1; d < 256; d <<= 1) {
            const int o = (t >= d) ? sc[t - d] : 0;
            __syncthreads();
            acc += o;
            sc[t] = acc;
            __syncthreads();
        }
        const int ex = acc - c + bbase[b];
        if (node < NN) {
            rowptr[node] = ex;
            if (node == NN - 1) rowptr[NN] = ex + c;
        }
        // per-wave cursors (each wave re-reads the same elements it histed)
        cnt4[0][t] = ex;
        cnt4[1][t] = ex + c0;
        cnt4[2][t] = ex + c0 + c1;
        cnt4[3][t] = ex + c0 + c1 + c2;
        __syncthreads();
        for (int i = t; i < n_e; i += 256) {
            const int v = p[i];
            const int pos = atomicAdd(&cnt4[wv][v >> 17], 1);
            csr[pos] = v & 0x1FFFF;
        }
        return;
    }

    const int tile = blockIdx.x - NB;
    const int row0 = tile * 64;
    const int l    = t & 63;
    const int l15  = l & 15;
    const int lk8  = (l >> 4) << 3;
    const int colw = wv << 5;

    f16x8 bf[2][4];
#pragma unroll
    for (int ct = 0; ct < 2; ++ct)
#pragma unroll
        for (int kt = 0; kt < 4; ++kt)
            bf[ct][kt] = *(const f16x8*)&Wt[(colw + ct * 16 + l15) * DIM + kt * 32 + lk8];

    f32x4 acc[4][2];
#pragma unroll
    for (int rt = 0; rt < 4; ++rt)
#pragma unroll
        for (int ct = 0; ct < 2; ++ct) acc[rt][ct] = (f32x4){0.f, 0.f, 0.f, 0.f};

#pragma unroll
    for (int rt = 0; rt < 4; ++rt) {
        int row = row0 + rt * 16 + l15;
        row = min(row, NN - 1);
        f16x8 a[4];
#pragma unroll
        for (int kt = 0; kt < 4; ++kt) {
            const int k0 = kt * 32 + lk8;
            const float4 v0 = *(const float4*)&inF[row * DIM + k0];
            const float4 v1 = *(const float4*)&inF[row * DIM + k0 + 4];
            f16x8 v;
            v[0] = (_Float16)v0.x; v[1] = (_Float16)v0.y;
            v[2] = (_Float16)v0.z; v[3] = (_Float16)v0.w;
            v[4] = (_Float16)v1.x; v[5] = (_Float16)v1.y;
            v[6] = (_Float16)v1.z; v[7] = (_Float16)v1.w;
            a[kt] = v;
        }
#pragma unroll
        for (int ct = 0; ct < 2; ++ct)
#pragma unroll
            for (int kt = 0; kt < 4; ++kt)
                acc[rt][ct] = __builtin_amdgcn_mfma_f32_16x16x32_f16(a[kt], bf[ct][kt],
                                                                    acc[rt][ct], 0, 0, 0);
    }

    // epilogue: stage (no dinv), then 256B-contiguous stores
#pragma unroll
    for (int rt = 0; rt < 4; ++rt)
#pragma unroll
        for (int r = 0; r < 4; ++r) {
            const int lr = rt * 16 + ((l >> 4) << 2) + r;
            st[lr][colw + l15]      = (_Float16)acc[rt][0][r];
            st[lr][colw + 16 + l15] = (_Float16)acc[rt][1][r];
        }
    __syncthreads();
#pragma unroll
    for (int i = 0; i < 4; ++i) {
        const int lr  = (wv << 4) + (i << 2) + (l >> 4);
        const int row = row0 + lr;
        if (row < NN) {
            const uint4 v = *(const uint4*)&st[lr][l15 << 3];
            *(uint4*)&outH[row * DIM + (l15 << 3)] = v;
        }
    }
}

// ---------------- GEMM2 (fp16 in, Wt2 vector frags, dinv epilogue, fp16 out) ----------------
__global__ void k_gemm2(const _Float16* __restrict__ inH, const _Float16* __restrict__ Wt,
                        const float* __restrict__ dinv, _Float16* __restrict__ outH) {
    __shared__ _Float16 st[64][STP];
    const int t = threadIdx.x;
    const int row0 = blockIdx.x * 64;
    const int wv   = t >> 6;
    const int l    = t & 63;
    const int l15  = l & 15;
    const int lk8  = (l >> 4) << 3;
    const int colw = wv << 5;

    f16x8 bf[2][4];
#pragma unroll
    for (int ct = 0; ct < 2; ++ct)
#pragma unroll
        for (int kt = 0; kt < 4; ++kt)
            bf[ct][kt] = *(const f16x8*)&Wt[(colw + ct * 16 + l15) * DIM + kt * 32 + lk8];

    f32x4 acc[4][2];
#pragma unroll
    for (int rt = 0; rt < 4; ++rt)
#pragma unroll
        for (int ct = 0; ct < 2; ++ct) acc[rt][ct] = (f32x4){0.f, 0.f, 0.f, 0.f};

#pragma unroll
    for (int rt = 0; rt < 4; ++rt) {
        int row = row0 + rt * 16 + l15;
        row = min(row, NN - 1);
        f16x8 a[4];
#pragma unroll
        for (int kt = 0; kt < 4; ++kt)
            a[kt] = *(const f16x8*)&inH[row * DIM + kt * 32 + lk8];
#pragma unroll
        for (int ct = 0; ct < 2; ++ct)
#pragma unroll
            for (int kt = 0; kt < 4; ++kt)
                acc[rt][ct] = __builtin_amdgcn_mfma_f32_16x16x32_f16(a[kt], bf[ct][kt],
                                                                    acc[rt][ct], 0, 0, 0);
    }

#pragma unroll
    for (int rt = 0; rt < 4; ++rt)
#pragma unroll
        for (int r = 0; r < 4; ++r) {
            const int lr = rt * 16 + ((l >> 4) << 2) + r;
            const float d = dinv[min(row0 + lr, NN - 1)];
            st[lr][colw + l15]      = (_Float16)(acc[rt][0][r] * d);
            st[lr][colw + 16 + l15] = (_Float16)(acc[rt][1][r] * d);
        }
    __syncthreads();
#pragma unroll
    for (int i = 0; i < 4; ++i) {
        const int lr  = (wv << 4) + (i << 2) + (l >> 4);
        const int row = row0 + lr;
        if (row < NN) {
            const uint4 v = *(const uint4*)&st[lr][l15 << 3];
            *(uint4*)&outH[row * DIM + (l15 << 3)] = v;
        }
    }
}

// ---------------- gather1 (deferred dinv): aggH[n] = half(relu(dinv[n]*S + b1)),
//                  S = h[n]*dinv[n] + sum_s h[s]*dinv[s] ----------------
__global__ void k_gather1(const _Float16* __restrict__ hsp, _Float16* __restrict__ aggH,
                          const int* __restrict__ csr, const int* __restrict__ rowptr,
                          const float* __restrict__ dinv, const float* __restrict__ bias) {
    const __half* __restrict__ hs = (const __half*)hsp;
    const int w = (blockIdx.x * blockDim.x + threadIdx.x) >> 6;
    if (w >= NN) return;
    const int lane = threadIdx.x & 63;
    const int off  = lane << 1;

    const int start = __builtin_amdgcn_readfirstlane(rowptr[w]);
    const int end   = __builtin_amdgcn_readfirstlane(rowptr[w + 1]);
    const float dw  = dinv[w];

    float2 a0 = {0.f, 0.f}, a1 = {0.f, 0.f}, a2 = {0.f, 0.f}, a3 = {0.f, 0.f};
    {   // self-loop: h[w]*dinv[w]
        const float2 v = __half22float2(*(const __half2*)&hs[w * DIM + off]);
        a0.x = dw * v.x; a0.y = dw * v.y;
    }

    int j = start;
    for (; j + 7 < end; j += 8) {
        const int s0 = __builtin_amdgcn_readfirstlane(csr[j]);
        const int s1 = __builtin_amdgcn_readfirstlane(csr[j + 1]);
        const int s2 = __builtin_amdgcn_readfirstlane(csr[j + 2]);
        const int s3 = __builtin_amdgcn_readfirstlane(csr[j + 3]);
        const int s4 = __builtin_amdgcn_readfirstlane(csr[j + 4]);
        const int s5 = __builtin_amdgcn_readfirstlane(csr[j + 5]);
        const int s6 = __builtin_amdgcn_readfirstlane(csr[j + 6]);
        const int s7 = __builtin_amdgcn_readfirstlane(csr[j + 7]);
        const float d0 = dinv[s0], d1 = dinv[s1], d2 = dinv[s2], d3 = dinv[s3];
        const float d4 = dinv[s4], d5 = dinv[s5], d6 = dinv[s6], d7 = dinv[s7];
        const float2 v0 = __half22float2(*(const __half2*)&hs[s0 * DIM + off]);
        const float2 v1 = __half22float2(*(const __half2*)&hs[s1 * DIM + off]);
        const float2 v2 = __half22float2(*(const __half2*)&hs[s2 * DIM + off]);
        const float2 v3 = __half22float2(*(const __half2*)&hs[s3 * DIM + off]);
        const float2 v4 = __half22float2(*(const __half2*)&hs[s4 * DIM + off]);
        const float2 v5 = __half22float2(*(const __half2*)&hs[s5 * DIM + off]);
        const float2 v6 = __half22float2(*(const __half2*)&hs[s6 * DIM + off]);
        const float2 v7 = __half22float2(*(const __half2*)&hs[s7 * DIM + off]);
        a0.x = fmaf(d0, v0.x, a0.x); a0.y = fmaf(d0, v0.y, a0.y);
        a1.x = fmaf(d1, v1.x, a1.x); a1.y = fmaf(d1, v1.y, a1.y);
        a2.x = fmaf(d2, v2.x, a2.x); a2.y = fmaf(d2, v2.y, a2.y);
        a3.x = fmaf(d3, v3.x, a3.x); a3.y = fmaf(d3, v3.y, a3.y);
        a0.x = fmaf(d4, v4.x, a0.x); a0.y = fmaf(d4, v4.y, a0.y);
        a1.x = fmaf(d5, v5.x, a1.x); a1.y = fmaf(d5, v5.y, a1.y);
        a2.x = fmaf(d6, v6.x, a2.x); a2.y = fmaf(d6, v6.y, a2.y);
        a3.x = fmaf(d7, v7.x, a3.x); a3.y = fmaf(d7, v7.y, a3.y);
    }
    for (; j < end; ++j) {
        const int s0 = __builtin_amdgcn_readfirstlane(csr[j]);
        const float d0 = dinv[s0];
        const float2 v0 = __half22float2(*(const __half2*)&hs[s0 * DIM + off]);
        a0.x = fmaf(d0, v0.x, a0.x); a0.y = fmaf(d0, v0.y, a0.y);
    }

    const float2 bb = {bias[off], bias[off + 1]};
    float2 r = {a0.x + a1.x + a2.x + a3.x, a0.y + a1.y + a2.y + a3.y};
    r.x = fmaxf(fmaf(dw, r.x, bb.x), 0.f);
    r.y = fmaxf(fmaf(dw, r.y, bb.y), 0.f);
    *(__half2*)&aggH[w * DIM + off] = __floats2half2_rn(r.x, r.y);
}

// ---------------- gather2 (hs2 pre-scaled): out = dinv*S + b2 (fp32) ----------------
__global__ void k_gather2(const _Float16* __restrict__ hsp, float* __restrict__ outF,
                          const int* __restrict__ csr, const int* __restrict__ rowptr,
                          const float* __restrict__ dinv, const float* __restrict__ bias) {
    const __half* __restrict__ hs = (const __half*)hsp;
    const int w = (blockIdx.x * blockDim.x + threadIdx.x) >> 6;
    if (w >= NN) return;
    const int lane = threadIdx.x & 63;
    const int off  = lane << 1;

    const int start = __builtin_amdgcn_readfirstlane(rowptr[w]);
    const int end   = __builtin_amdgcn_readfirstlane(rowptr[w + 1]);

    float2 a0 = __half22float2(*(const __half2*)&hs[w * DIM + off]);  // self-loop
    float2 a1 = {0.f, 0.f}, a2 = {0.f, 0.f}, a3 = {0.f, 0.f};

    int j = start;
    for (; j + 7 < end; j += 8) {
        const int s0 = __builtin_amdgcn_readfirstlane(csr[j]);
        const int s1 = __builtin_amdgcn_readfirstlane(csr[j + 1]);
        const int s2 = __builtin_amdgcn_readfirstlane(csr[j + 2]);
        const int s3 = __builtin_amdgcn_readfirstlane(csr[j + 3]);
        const int s4 = __builtin_amdgcn_readfirstlane(csr[j + 4]);
        const int s5 = __builtin_amdgcn_readfirstlane(csr[j + 5]);
        const int s6 = __builtin_amdgcn_readfirstlane(csr[j + 6]);
        const int s7 = __builtin_amdgcn_readfirstlane(csr[j + 7]);
        const float2 v0 = __half22float2(*(const __half2*)&hs[s0 * DIM + off]);
        const float2 v1 = __half22float2(*(const __half2*)&hs[s1 * DIM + off]);
        const float2 v2 = __half22float2(*(const __half2*)&hs[s2 * DIM + off]);
        const float2 v3 = __half22float2(*(const __half2*)&hs[s3 * DIM + off]);
        const float2 v4 = __half22float2(*(const __half2*)&hs[s4 * DIM + off]);
        const float2 v5 = __half22float2(*(const __half2*)&hs[s5 * DIM + off]);
        const float2 v6 = __half22float2(*(const __half2*)&hs[s6 * DIM + off]);
        const float2 v7 = __half22float2(*(const __half2*)&hs[s7 * DIM + off]);
        a0.x += v0.x; a0.y += v0.y;
        a1.x += v1.x; a1.y += v1.y;
        a2.x += v2.x; a2.y += v2.y;
        a3.x += v3.x; a3.y += v3.y;
        a0.x += v4.x; a0.y += v4.y;
        a1.x += v5.x; a1.y += v5.y;
        a2.x += v6.x; a2.y += v6.y;
        a3.x += v7.x; a3.y += v7.y;
    }
    for (; j < end; ++j) {
        const int s0 = __builtin_amdgcn_readfirstlane(csr[j]);
        const float2 v0 = __half22float2(*(const __half2*)&hs[s0 * DIM + off]);
        a0.x += v0.x; a0.y += v0.y;
    }

    const float d = dinv[w];
    const float2 bb = {bias[off], bias[off + 1]};
    float2 r = {a0.x + a1.x + a2.x + a3.x, a0.y + a1.y + a2.y + a3.y};
    float2 o;
    o.x = fmaf(d, r.x, bb.x);
    o.y = fmaf(d, r.y, bb.y);
    *(float2*)&outF[w * DIM + off] = o;
}

extern "C" void kernel_launch(void* const* d_in, const int* in_sizes, int n_in,
                              void* d_out, int out_size, void* d_ws, size_t ws_size,
                              hipStream_t stream) {
    const float* x  = (const float*)d_in[0];
    const int*   ei = (const int*)d_in[1];
    const float* W1 = (const float*)d_in[2];
    const float* b1 = (const float*)d_in[3];
    const float* W2 = (const float*)d_in[4];
    const float* b2 = (const float*)d_in[5];
    float* out = (float*)d_out;

    const int E = in_sizes[1] / 2;
    const int* src = ei;        // edge_index[0]
    const int* dst = ei + E;    // edge_index[1]

    char* ws = (char*)d_ws;
    float*    dinv   = (float*)(ws);                           // NN floats
    int*      rowptr = (int*)  (ws + (2  << 20));              // NN+1 ints
    int*      bbase  = (int*)  (ws + (3  << 20));              // NB ints
    int*      bcur   = (int*)  (ws + (3  << 20) + 65536);      // NB ints
    _Float16* Wt1    = (_Float16*)(ws + (3 << 20) + 131072);   // 16384 halves
    _Float16* Wt2    = (_Float16*)(ws + (3 << 20) + 196608);   // 16384 halves
    int*      csr    = (int*)  (ws + (4  << 20));              // E ints (6.4 MB)
    int*      binbuf = (int*)  (ws + (11 << 20));              // NB*BCAP ints (8.0 MB)
    _Float16* hs     = (_Float16*)(ws + (20 << 20));           // 25.6 MB
    _Float16* aggH   = (_Float16*)(ws + (47 << 20));           // 25.6 MB
    _Float16* hs2    = (_Float16*)(ws + (74 << 20));           // 25.6 MB

    const int ABLK = (E + 4095) / 4096;                        // 391

    // ---- init (bcur zero + W transpose/convert) + CSR binning ----
    k_init <<<130, 256, 0, stream>>>(W1, W2, bcur, Wt1, Wt2);
    k_binA <<<ABLK, 256, 0, stream>>>(src, dst, bcur, binbuf, E);
    k_scan2<<<1, 512, 0, stream>>>(bcur, bbase, NB);

    // ---- layer 1: fill (hist+rowptr+dinv+csr; 391 blocks) + GEMM1 (1563 tiles) ----
    k_gemm1<<<NB + GTILES, 256, 0, stream>>>(x, Wt1, hs, bbase, bcur, binbuf,
                                             rowptr, dinv, csr);
    k_gather1<<<(NN * 64) / 256, 256, 0, stream>>>(hs, aggH, csr, rowptr, dinv, b1);

    // ---- layer 2 ----
    k_gemm2<<<GTILES, 256, 0, stream>>>(aggH, Wt2, dinv, hs2);
    k_gather2<<<(NN * 64) / 256, 256, 0, stream>>>(hs2, out, csr, rowptr, dinv, b2);
}